// Round 7
// baseline (376.363 us; speedup 1.0000x reference)
//
#include <hip/hip_runtime.h>
#include <hip/hip_bf16.h>

// Problem constants
#define BDIM 8
#define TDIM 256
#define UDIM 64
#define HDIM 640
#define VDIM 1024
#define MDIM (BDIM * TDIM * UDIM)   // 131072

// GEMM tiling: 128x128 tile, BK=32, 4 waves, NBUF=3 ring (48KB LDS)
// -> 3 blocks/CU, ONE barrier per K-tile, prefetch distance 2.
#define BM 128
#define BN 128
#define BK 32
#define NT (HDIM / BK)              // 20 K-tiles
#define NBUF 3

typedef __attribute__((ext_vector_type(8))) short short8;   // 8 bf16 (16B)
typedef __attribute__((ext_vector_type(4))) float f32x4;

__device__ __forceinline__ ushort f2bf(float x) {
    union { float f; unsigned int u; } v; v.f = x;
    unsigned int r = (v.u + 0x7fffu + ((v.u >> 16) & 1u)) >> 16;  // RNE
    return (ushort)r;
}

// Prep 1: W (V x H fp32) -> bf16
__global__ void cvt_w_kernel(const float* __restrict__ W, ushort* __restrict__ Wb) {
    int i = (blockIdx.x * 256 + threadIdx.x) * 4;
    f32x4 w = *(const f32x4*)(W + i);
    ushort4 o;
    o.x = f2bf(w[0]); o.y = f2bf(w[1]); o.z = f2bf(w[2]); o.w = f2bf(w[3]);
    *(ushort4*)(Wb + i) = o;
}

// Prep 2: h[m][k] = relu(f[b][t][k] + p[b][u][k]) as bf16
__global__ __launch_bounds__(256) void build_h_kernel(
    const float* __restrict__ f, const float* __restrict__ p,
    ushort* __restrict__ h)
{
    const int tid = threadIdx.x;
    const int row = (blockIdx.x << 5) + (tid >> 3);
    const int j0  = tid & 7;
    const int b = row >> 14;
    const int t = (row >> 6) & (TDIM - 1);
    const int u = row & (UDIM - 1);
    const float* frow = f + (size_t)(b * TDIM + t) * HDIM;
    const float* prow = p + (size_t)(b * UDIM + u) * HDIM;
    ushort* hrow = h + (size_t)row * HDIM;
    #pragma unroll
    for (int it = 0; it < HDIM / 64; ++it) {
        const int k = (j0 + it * 8) * 8;
        f32x4 f0 = *(const f32x4*)(frow + k);
        f32x4 f1 = *(const f32x4*)(frow + k + 4);
        f32x4 p0 = *(const f32x4*)(prow + k);
        f32x4 p1 = *(const f32x4*)(prow + k + 4);
        short8 hv;
        #pragma unroll
        for (int e = 0; e < 4; ++e) {
            float a0 = fmaxf(f0[e] + p0[e], 0.0f);
            float a1 = fmaxf(f1[e] + p1[e], 0.0f);
            hv[e]     = (short)f2bf(a0);
            hv[e + 4] = (short)f2bf(a1);
        }
        *(short8*)(hrow + k) = hv;
    }
}

#define GLDS(srcptr, ldsptr)                                                   \
    __builtin_amdgcn_global_load_lds(                                          \
        (const __attribute__((address_space(1))) void*)(srcptr),               \
        (__attribute__((address_space(3))) void*)(ldsptr), 16, 0, 0)

// 128x128 tile, BK=32, 4 waves (2x2), NBUF=3 ring, 48KB LDS, 3 blocks/CU.
// ONE barrier per tile; prefetch distance 2; vmcnt(4) before barrier.
//
// Epoch audit (body: vmcnt; barrier_t; read buf[t%3]; STG(t+2 -> buf[(t+2)%3]);
// MFMA):
//  - Strict epochs: a wave passes barrier_{t+1} only after ALL waves arrived,
//    so activities of epoch E_t never overlap E_{t+1} activities.
//  - Within E_t: reads hit buf[t%3], writes hit buf[(t+2)%3] — disjoint (2!=0
//    mod 3).  SAFE.
//  - Reads of buf[t%3] valid: every wave executed ITS vmcnt(4) (retiring its
//    tile-t loads; in-order vmem retire) BEFORE barrier_t.  SAFE.
//  - Ledger: at vmcnt, outstanding = {t:4, t+1:4} = 8 -> vmcnt(4) retires
//    exactly tile t; STG(t+2) later raises to 8 again. Drain only at t=NT-1.
// Swizzle (rounds 3/4: measured 0 conflicts): 16B-chunk slot = j ^ ((row>>1)&3),
// pre-swizzled on the GLOBAL source; frag reads apply the same XOR.
__global__ __launch_bounds__(256, 3) void hgemm128_kernel(
    const ushort* __restrict__ h,     // (M,H) bf16
    const ushort* __restrict__ Wb,    // (V,H) bf16
    const float* __restrict__ bias,   // (V)
    float* __restrict__ out)          // (M,V) fp32
{
    __shared__ ushort Ash[NBUF][BM * BK];  // 3 x 8 KB
    __shared__ ushort Bsh[NBUF][BN * BK];  // 3 x 8 KB

    const int tid  = threadIdx.x;
    const int lane = tid & 63;
    const int wave = tid >> 6;   // 0..3
    const int wm   = wave >> 1;  // 0..1 -> 64-row half
    const int wn   = wave & 1;   // 0..1 -> 64-col half

    // Bijective XCD swizzle: 8192 blocks (%8==0). XCD x runs works
    // [x*1024,(x+1)*1024): 8 ntiles of one mtile consecutive -> A panels
    // L2-reused 8x, Wb (1.25MB) L2-resident per XCD.
    const int bid   = blockIdx.x;
    const int work  = (bid & 7) * 1024 + (bid >> 3);
    const int mtile = work >> 3;
    const int ntile = work & 7;
    const int m0 = mtile * BM;
    const int v0 = ntile * BN;

    const ushort* hbase = h  + (size_t)m0 * HDIM;
    const ushort* wbase = Wb + (size_t)v0 * HDIM;

    // Staging map: per buffer 512 x 16B chunks, 2 per thread (i=0,1).
    // LDS slot s = i*256+tid: row = s>>2, j = s&3; holds global chunk
    // j ^ ((row>>1)&3).  Dest = linear (wave*64 + lane) chunks.
    const int r0a = tid >> 2;          // i=0 row
    const int r0b = r0a + 64;          // i=1 row
    const int j0  = tid & 3;
    const size_t sof0 = (size_t)r0a * HDIM + (j0 ^ ((r0a >> 1) & 3)) * 8;
    const size_t sof1 = (size_t)r0b * HDIM + (j0 ^ ((r0b >> 1) & 3)) * 8;
    const int u0 = (wave * 64) * 8;          // ushort idx, i=0 (lane*16B by HW)
    const int u1 = (256 + wave * 64) * 8;    // i=1

    // Fragment offsets (ushort idx within one buffer), kt-independent.
    int aoff[4], boff[4];
    #pragma unroll
    for (int mi = 0; mi < 4; ++mi) {
        const int r = wm * 64 + mi * 16 + (lane & 15);
        aoff[mi] = (r * 4 + ((lane >> 4) ^ ((r >> 1) & 3))) * 8;
    }
    #pragma unroll
    for (int ni = 0; ni < 4; ++ni) {
        const int r = wn * 64 + ni * 16 + (lane & 15);
        boff[ni] = (r * 4 + ((lane >> 4) ^ ((r >> 1) & 3))) * 8;
    }

    f32x4 acc[4][4];
    #pragma unroll
    for (int i = 0; i < 4; ++i)
        #pragma unroll
        for (int j = 0; j < 4; ++j)
            acc[i][j] = (f32x4)0.0f;

#define STG(kt, bf) do {                                                       \
        GLDS(hbase + sof0 + (kt) * BK, &Ash[bf][u0]);                          \
        GLDS(hbase + sof1 + (kt) * BK, &Ash[bf][u1]);                          \
        GLDS(wbase + sof0 + (kt) * BK, &Bsh[bf][u0]);                          \
        GLDS(wbase + sof1 + (kt) * BK, &Bsh[bf][u1]);                          \
    } while (0)

    STG(0, 0);
    STG(1, 1);

    int d = 0;          // buffer holding tile t
    int e = 2;          // buffer receiving tile t+2
    #pragma unroll 1
    for (int t = 0; t < NT; ++t) {
        if (t < NT - 1) { asm volatile("s_waitcnt vmcnt(4)" ::: "memory"); }
        else            { asm volatile("s_waitcnt vmcnt(0)" ::: "memory"); }
        __builtin_amdgcn_sched_barrier(0);
        __builtin_amdgcn_s_barrier();          // tile t landed for all waves
        __builtin_amdgcn_sched_barrier(0);

        short8 afr[4], bfr[4];
        #pragma unroll
        for (int q = 0; q < 4; ++q) {
            afr[q] = *(const short8*)(&Ash[d][aoff[q]]);
            bfr[q] = *(const short8*)(&Bsh[d][boff[q]]);
        }

        if (t + 2 < NT) STG(t + 2, e);         // into buf[(t+2)%3]

        __builtin_amdgcn_s_setprio(1);
        #pragma unroll
        for (int mi = 0; mi < 4; ++mi)
            #pragma unroll
            for (int ni = 0; ni < 4; ++ni)
                acc[mi][ni] = __builtin_amdgcn_mfma_f32_16x16x32_bf16(
                    afr[mi], bfr[ni], acc[mi][ni], 0, 0, 0);
        __builtin_amdgcn_s_setprio(0);
        __builtin_amdgcn_sched_barrier(0);     // pin body order across iters

        d = (d == NBUF - 1) ? 0 : d + 1;
        e = (e == NBUF - 1) ? 0 : e + 1;
    }
#undef STG

    // Epilogue: C/D col = lane&15, row = (lane>>4)*4 + reg
    #pragma unroll
    for (int ni = 0; ni < 4; ++ni) {
        const int col = v0 + wn * 64 + ni * 16 + (lane & 15);
        const float bv = bias[col];
        #pragma unroll
        for (int mi = 0; mi < 4; ++mi) {
            const int rbase = m0 + wm * 64 + mi * 16 + ((lane >> 4) << 2);
            #pragma unroll
            for (int reg = 0; reg < 4; ++reg) {
                out[(size_t)(rbase + reg) * VDIM + col] = acc[mi][ni][reg] + bv;
            }
        }
    }
}

// ---------------- fallback fused kernel (round-1 verified) ----------------
template <bool USE_WB>
__global__ __launch_bounds__(256) void joint_gemm_kernel(
    const float* __restrict__ f, const float* __restrict__ p,
    const float* __restrict__ Wf, const ushort* __restrict__ Wb,
    const float* __restrict__ bias, float* __restrict__ out)
{
    __shared__ ushort Alds[128 * 64];
    __shared__ ushort Blds[128 * 64];

    const int tid  = threadIdx.x;
    const int lane = tid & 63;
    const int wave = tid >> 6;
    const int wm   = wave >> 1;
    const int wn   = wave & 1;

    const int bid   = blockIdx.x;
    const int work  = (bid & 7) * 1024 + (bid >> 3);
    const int mtile = work >> 3;
    const int ntile = work & 7;
    const int m0 = mtile * 128;
    const int v0 = ntile * 128;

    const int b  = m0 >> 14;
    const int t0 = (m0 >> 6) & (TDIM - 1);

    const float*  fbase = f + (size_t)(b * TDIM + t0) * HDIM;
    const float*  pbase = p + (size_t)b * UDIM * HDIM;
    const ushort* wbbase = Wb + (size_t)v0 * HDIM;
    const float*  wfbase = Wf + (size_t)v0 * HDIM;

    f32x4 acc[4][4];
    #pragma unroll
    for (int i = 0; i < 4; ++i)
        #pragma unroll
        for (int j = 0; j < 4; ++j)
            acc[i][j] = (f32x4)0.0f;

    for (int kt = 0; kt < HDIM / 64; ++kt) {
        const int k0 = kt * 64;
        __syncthreads();

        if (USE_WB) {
            #pragma unroll
            for (int it = 0; it < 4; ++it) {
                const int c   = it * 256 + tid;
                const int row = c >> 3;
                const int j   = c & 7;
                const ushort* src = wbbase + row * HDIM + k0 + ((j ^ (row & 7)) << 3);
                GLDS(src, &Blds[(it * 256 + wave * 64) * 8]);
            }
        } else {
            #pragma unroll
            for (int it = 0; it < 4; ++it) {
                const int c   = it * 256 + tid;
                const int row = c >> 3;
                const int j   = c & 7;
                const float* wp = wfbase + row * HDIM + k0 + j * 8;
                f32x4 w0 = *(const f32x4*)wp;
                f32x4 w1 = *(const f32x4*)(wp + 4);
                short8 wv;
                #pragma unroll
                for (int e = 0; e < 4; ++e) {
                    wv[e]     = (short)f2bf(w0[e]);
                    wv[e + 4] = (short)f2bf(w1[e]);
                }
                *(short8*)(&Blds[(row * 8 + (j ^ (row & 7))) * 8]) = wv;
            }
        }

        #pragma unroll
        for (int it = 0; it < 4; ++it) {
            const int c   = it * 256 + tid;
            const int row = c >> 3;
            const int j   = c & 7;
            const float* fp_ = fbase + (row >> 6) * HDIM + k0 + j * 8;
            const float* pp_ = pbase + (row & 63) * HDIM + k0 + j * 8;
            f32x4 f0 = *(const f32x4*)fp_;
            f32x4 f1 = *(const f32x4*)(fp_ + 4);
            f32x4 p0 = *(const f32x4*)pp_;
            f32x4 p1 = *(const f32x4*)(pp_ + 4);
            short8 hv;
            #pragma unroll
            for (int e = 0; e < 4; ++e) {
                float a0 = fmaxf(f0[e] + p0[e], 0.0f);
                float a1 = fmaxf(f1[e] + p1[e], 0.0f);
                hv[e]     = (short)f2bf(a0);
                hv[e + 4] = (short)f2bf(a1);
            }
            *(short8*)(&Alds[(row * 8 + (j ^ (row & 7))) * 8]) = hv;
        }

        __syncthreads();

        #pragma unroll
        for (int ks = 0; ks < 2; ++ks) {
            short8 afr[4], bfr[4];
            #pragma unroll
            for (int mi = 0; mi < 4; ++mi) {
                const int r = wm * 64 + mi * 16 + (lane & 15);
                const int j = ks * 4 + (lane >> 4);
                afr[mi] = *(const short8*)(&Alds[(r * 8 + (j ^ (r & 7))) * 8]);
            }
            #pragma unroll
            for (int ni = 0; ni < 4; ++ni) {
                const int r = wn * 64 + ni * 16 + (lane & 15);
                const int j = ks * 4 + (lane >> 4);
                bfr[ni] = *(const short8*)(&Blds[(r * 8 + (j ^ (r & 7))) * 8]);
            }
            #pragma unroll
            for (int mi = 0; mi < 4; ++mi)
                #pragma unroll
                for (int ni = 0; ni < 4; ++ni)
                    acc[mi][ni] = __builtin_amdgcn_mfma_f32_16x16x32_bf16(
                        afr[mi], bfr[ni], acc[mi][ni], 0, 0, 0);
        }
    }

    #pragma unroll
    for (int ni = 0; ni < 4; ++ni) {
        const int col = v0 + wn * 64 + ni * 16 + (lane & 15);
        const float bv = bias[col];
        #pragma unroll
        for (int mi = 0; mi < 4; ++mi) {
            const int rbase = m0 + wm * 64 + mi * 16 + ((lane >> 4) << 2);
            #pragma unroll
            for (int reg = 0; reg < 4; ++reg) {
                out[(size_t)(rbase + reg) * VDIM + col] = acc[mi][ni][reg] + bv;
            }
        }
    }
}

extern "C" void kernel_launch(void* const* d_in, const int* in_sizes, int n_in,
                              void* d_out, int out_size, void* d_ws, size_t ws_size,
                              hipStream_t stream) {
    const float* f    = (const float*)d_in[0];   // (8,256,640)
    const float* p    = (const float*)d_in[1];   // (8,64,640)
    const float* W    = (const float*)d_in[2];   // (1024,640)
    const float* bias = (const float*)d_in[3];   // (1024)
    float* out = (float*)d_out;                  // (8,256,64,1024) fp32

    const size_t wb_bytes = (size_t)VDIM * HDIM * sizeof(ushort);   // 1.25 MB
    const size_t h_bytes  = (size_t)MDIM * HDIM * sizeof(ushort);   // 160 MB

    if (ws_size >= wb_bytes + h_bytes) {
        ushort* Wb = (ushort*)d_ws;
        ushort* h  = (ushort*)((char*)d_ws + wb_bytes);
        cvt_w_kernel<<<(VDIM * HDIM) / 1024, 256, 0, stream>>>(W, Wb);
        build_h_kernel<<<MDIM / 32, 256, 0, stream>>>(f, p, h);
        const int grid = (MDIM / BM) * (VDIM / BN);   // 8192
        hgemm128_kernel<<<grid, 256, 0, stream>>>(h, Wb, bias, out);
    } else if (ws_size >= wb_bytes) {
        ushort* Wb = (ushort*)d_ws;
        cvt_w_kernel<<<(VDIM * HDIM) / 1024, 256, 0, stream>>>(W, Wb);
        joint_gemm_kernel<true><<<(MDIM / 128) * (VDIM / 128), 256, 0, stream>>>(
            f, p, W, Wb, bias, out);
    } else {
        joint_gemm_kernel<false><<<(MDIM / 128) * (VDIM / 128), 256, 0, stream>>>(
            f, p, W, nullptr, bias, out);
    }
}